// Round 1
// baseline (182.614 us; speedup 1.0000x reference)
//
#include <hip/hip_runtime.h>

#define NGRAPH 4096
#define NNODE  64
#define NDIM   128
#define NLAYER 3
#define PH 136   // sh pitch (bf16): 68 dwords === 4 mod 32 -> bank-uniform b128 row reads

typedef __attribute__((ext_vector_type(8))) short short8;
typedef __attribute__((ext_vector_type(4))) float f32x4;
typedef __bf16 bf16x2 __attribute__((ext_vector_type(2)));

union S8 { short8 s8; unsigned d[4]; };

static __device__ inline ushort f2bf(float f) {  // RNE fp32 -> bf16 (fallback path)
  unsigned u = __float_as_uint(f);
  u += 0x7FFF + ((u >> 16) & 1);
  return (ushort)(u >> 16);
}

// packed fp32x2 -> bf16x2 in one HW instr on gfx950 (v_cvt_pk_bf16_f32)
static __device__ inline unsigned pkbf(float x, float y) {
#if __has_builtin(__builtin_amdgcn_cvt_pk_bf16_f32)
  bf16x2 v = __builtin_amdgcn_cvt_pk_bf16_f32(x, y);
  return __builtin_bit_cast(unsigned, v);
#else
  return (unsigned)f2bf(x) | ((unsigned)f2bf(y) << 16);
#endif
}

// W in bf16, native [l][k_out][d] layout (B-frag reads W rows directly).
__device__ __align__(16) ushort g_wbf[NLAYER * NDIM * NDIM];

__global__ __launch_bounds__(256) void convert_w(const float* __restrict__ W) {
  int i = blockIdx.x * 256 + threadIdx.x;   // 192 blocks, exact
  g_wbf[i] = f2bf(W[i]);
}

// R9 restructure: LDS-pipe was the bottleneck (192 ds_read_b128/block-layer,
// MfmaUtil 18%, HBM 6%).  (1) (I+A) B-frags are layer-invariant -> hoisted to
// registers once per block, loaded straight from global adj (sadj buffer and
// its staging deleted; m2 is now register-only).  (2) 4 waves x 32-wide kout
// slabs: ah A-frags loaded once per k-step feed BOTH 16-slabs -> h LDS reads
// halved.  (3) single h buffer (17 KB LDS), two barriers/layer.
__global__ __launch_bounds__(256, 4) void mpnn_mfma(
    const int* __restrict__ fps, const float* __restrict__ adj,
    const float* __restrict__ emb, const float* __restrict__ bias,
    float* __restrict__ out) {
  __shared__ __align__(16) ushort sh[NNODE * PH];    // h (single buffer) 17408 B

  const int g    = blockIdx.x;
  const int t    = threadIdx.x;
  const int w    = t >> 6;        // wave 0..3
  const int lane = t & 63;
  const int r    = lane & 15;     // MFMA row/col index
  const int q    = lane >> 4;     // quad 0..3
  const int n0   = w << 5;        // wave's 32-wide k_out region (two 16-slabs)

  // bpermute addresses for the z C-frag -> A-frag quad permute (R8-verified mapping)
  const int addr0 = (r + 32 * (q & 1)) << 2;   // p = 0,1
  const int addr1 = addr0 + 64;                // p = 2,3
  const bool hiQ  = (q >= 2);                  // source register select (node>=16 within 32)

  // ---- gather h0 = bf16(emb[fps]) into sh ----
  const int* fg = fps + g * NNODE;
#pragma unroll
  for (int it = 0; it < 8; ++it) {
    int idx = it * 256 + t;               // 2048 float4s
    int n = idx >> 5;
    int c = (idx & 31) << 2;
    float4 v = *(const float4*)(emb + fg[n] * NDIM + c);
    uint2 u = {pkbf(v.x, v.y), pkbf(v.z, v.w)};
    *(uint2*)(sh + n * PH + c) = u;
  }

  // ---- (I+A) B-frags: global fp32 -> bf16 registers, once per block ----
  // frag[kh][nt] lane layout identical to the old sadj ds_read_b128:
  // B[k=kh*32+8q+e][col=nt*16+r] = (I+A)[col][k]
  const float* adjg = adj + (size_t)g * NNODE * NNODE;
  short8 fbr[2][4];
#pragma unroll
  for (int kh = 0; kh < 2; ++kh) {
#pragma unroll
    for (int nt = 0; nt < 4; ++nt) {
      int row = nt * 16 + r;
      int col = kh * 32 + 8 * q;
      const float* ap = adjg + row * NNODE + col;
      float4 v0 = *(const float4*)ap;
      float4 v1 = *(const float4*)(ap + 4);
      v0.x += (row == col + 0) ? 1.0f : 0.0f;   // fold residual: I + A
      v0.y += (row == col + 1) ? 1.0f : 0.0f;
      v0.z += (row == col + 2) ? 1.0f : 0.0f;
      v0.w += (row == col + 3) ? 1.0f : 0.0f;
      v1.x += (row == col + 4) ? 1.0f : 0.0f;
      v1.y += (row == col + 5) ? 1.0f : 0.0f;
      v1.z += (row == col + 6) ? 1.0f : 0.0f;
      v1.w += (row == col + 7) ? 1.0f : 0.0f;
      S8 u;
      u.d[0] = pkbf(v0.x, v0.y);
      u.d[1] = pkbf(v0.z, v0.w);
      u.d[2] = pkbf(v1.x, v1.y);
      u.d[3] = pkbf(v1.z, v1.w);
      fbr[kh][nt] = u.s8;
    }
  }

  // ---- bias for all layers, both slabs -> registers ----
  float bv[NLAYER][2];
#pragma unroll
  for (int l = 0; l < NLAYER; ++l) {
    bv[l][0] = bias[l * NDIM + n0 + r];
    bv[l][1] = bias[l * NDIM + n0 + 16 + r];
  }

  __syncthreads();

#pragma unroll 1   // real loop: avoid cross-layer load hoisting -> spill (R6 lesson)
  for (int l = 0; l < NLAYER; ++l) {
    const ushort* Wl = g_wbf + l * NDIM * NDIM;

    // ---- m1: z[node][n0-region(32)] = relu(h * W^T + b), two 16-slabs ----
    f32x4 acc[2][4];
#pragma unroll
    for (int s = 0; s < 2; ++s)
#pragma unroll
      for (int mt = 0; mt < 4; ++mt)
        acc[s][mt] = (f32x4){bv[l][s], bv[l][s], bv[l][s], bv[l][s]};
#pragma unroll
    for (int k0 = 0; k0 < NDIM; k0 += 32) {
      short8 ah[4];                       // loaded ONCE, feeds both slabs
#pragma unroll
      for (int mt = 0; mt < 4; ++mt)
        ah[mt] = *(const short8*)(sh + (mt * 16 + r) * PH + k0 + 8 * q);
#pragma unroll
      for (int s = 0; s < 2; ++s) {
        short8 bw = *(const short8*)(Wl + (n0 + s * 16 + r) * NDIM + k0 + 8 * q);
#pragma unroll
        for (int mt = 0; mt < 4; ++mt)
          acc[s][mt] = __builtin_amdgcn_mfma_f32_16x16x32_bf16(ah[mt], bw, acc[s][mt], 0, 0, 0);
      }
    }

    // ---- relu -> packed bf16 in registers ----
    unsigned zc[2][4][2];   // [slab][mt: node tile][node pair within quad-rows]
#pragma unroll
    for (int s = 0; s < 2; ++s)
#pragma unroll
      for (int mt = 0; mt < 4; ++mt) {
        f32x4 a = acc[s][mt];
        zc[s][mt][0] = pkbf(fmaxf(a[0], 0.f), fmaxf(a[1], 0.f));
        zc[s][mt][1] = pkbf(fmaxf(a[2], 0.f), fmaxf(a[3], 0.f));
      }

    // ---- m2: houtT[d in n0-region][node'] = zT * (I+A)^T — register-only ----
    f32x4 acc2[2][4];
#pragma unroll
    for (int s = 0; s < 2; ++s)
#pragma unroll
      for (int nt = 0; nt < 4; ++nt) acc2[s][nt] = (f32x4){0.f, 0.f, 0.f, 0.f};
#pragma unroll
    for (int s = 0; s < 2; ++s) {
#pragma unroll
      for (int kh = 0; kh < 2; ++kh) {
        S8 az;
#pragma unroll
        for (int p = 0; p < 4; ++p) {
          int comp = p & 1;
          int lo = __builtin_amdgcn_ds_bpermute((p < 2) ? addr0 : addr1,
                                                (int)zc[s][2 * kh][comp]);
          int hi = __builtin_amdgcn_ds_bpermute((p < 2) ? addr0 : addr1,
                                                (int)zc[s][2 * kh + 1][comp]);
          az.d[p] = (unsigned)(hiQ ? hi : lo);
        }
#pragma unroll
        for (int nt = 0; nt < 4; ++nt)
          acc2[s][nt] = __builtin_amdgcn_mfma_f32_16x16x32_bf16(az.s8, fbr[kh][nt], acc2[s][nt], 0, 0, 0);
      }
    }

    if (l < NLAYER - 1) {
      __syncthreads();   // all waves done READING sh (m1); safe to overwrite
#pragma unroll
      for (int s = 0; s < 2; ++s)
#pragma unroll
        for (int nt = 0; nt < 4; ++nt) {
          f32x4 a = acc2[s][nt];
          uint2 u = {pkbf(a[0], a[1]), pkbf(a[2], a[3])};
          *(uint2*)(sh + (nt * 16 + r) * PH + n0 + s * 16 + 4 * q) = u;
        }
      __syncthreads();   // writes visible before next layer's reads
    } else {
      // ---- sum-pool: out[g][d] = sum_node' h[node'][d] ----
#pragma unroll
      for (int s = 0; s < 2; ++s) {
        f32x4 sum;
#pragma unroll
        for (int i = 0; i < 4; ++i)
          sum[i] = acc2[s][0][i] + acc2[s][1][i] + acc2[s][2][i] + acc2[s][3][i];
#pragma unroll
        for (int m = 1; m <= 8; m <<= 1) {
          sum[0] += __shfl_xor(sum[0], m);
          sum[1] += __shfl_xor(sum[1], m);
          sum[2] += __shfl_xor(sum[2], m);
          sum[3] += __shfl_xor(sum[3], m);
        }
        if (r == 0) {
          float4 o = {sum[0], sum[1], sum[2], sum[3]};
          *(float4*)(out + (size_t)g * NDIM + n0 + s * 16 + 4 * q) = o;
        }
      }
    }
  }
}

extern "C" void kernel_launch(void* const* d_in, const int* in_sizes, int n_in,
                              void* d_out, int out_size, void* d_ws, size_t ws_size,
                              hipStream_t stream) {
  const int*   fps  = (const int*)d_in[0];
  const float* adj  = (const float*)d_in[1];
  const float* emb  = (const float*)d_in[2];
  const float* W    = (const float*)d_in[3];
  const float* bias = (const float*)d_in[4];
  float* out = (float*)d_out;

  hipLaunchKernelGGL(convert_w, dim3(192), dim3(256), 0, stream, W);
  hipLaunchKernelGGL(mpnn_mfma, dim3(NGRAPH), dim3(256), 0, stream,
                     fps, adj, emb, bias, out);
}